// Round 2
// baseline (922.278 us; speedup 1.0000x reference)
//
#include <hip/hip_runtime.h>
#include <hip/hip_bf16.h>

#define OUT_DIM 4096
#define IN_DIM  4096
#define RANK    64
#define M_DIM   16384   // B*S = 4*4096

typedef short  s16x8 __attribute__((ext_vector_type(8)));
typedef __bf16 b16x8 __attribute__((ext_vector_type(8)));
typedef float  f32x4 __attribute__((ext_vector_type(4)));

// ---- MFMA wrapper: tolerate either builtin signature (short8 or bf16x8) ----
template <typename T>
__device__ static inline auto mfma_sel(T a, T b, f32x4 c, int)
    -> decltype(__builtin_amdgcn_mfma_f32_16x16x32_bf16(a, b, c, 0, 0, 0)) {
  return __builtin_amdgcn_mfma_f32_16x16x32_bf16(a, b, c, 0, 0, 0);
}
template <typename T>
__device__ static inline f32x4 mfma_sel(T a, T b, f32x4 c, long) {
  return __builtin_amdgcn_mfma_f32_16x16x32_bf16(
      __builtin_bit_cast(b16x8, a), __builtin_bit_cast(b16x8, b), c, 0, 0, 0);
}
__device__ static inline f32x4 mfma_bf16(s16x8 a, s16x8 b, f32x4 c) {
  return mfma_sel(a, b, c, 0);
}

// ---- fp32 -> bf16 bits, round-to-nearest-even ----
__device__ static inline unsigned short f2bf(float f) {
  unsigned int u = __float_as_uint(f);
  u += 0x7fffu + ((u >> 16) & 1u);
  return (unsigned short)(u >> 16);
}

// ---- async global->LDS, 16B per lane ----
__device__ static inline void gload16(const unsigned short* g, unsigned short* l) {
  __builtin_amdgcn_global_load_lds(
      (const __attribute__((address_space(1))) void*)g,
      (__attribute__((address_space(3))) void*)l, 16, 0, 0);
}

// ============ kernel 1: sigma gating + scaled factors ============
// A1[o][r] = U_top[o][r] * relu(S_top[r]*alpha[r]+beta[r]) ; A2[o][r] = U_tail[o][r]*S_tail[r]
__global__ void prep_kernel(const float* __restrict__ U_top, const float* __restrict__ S_top,
                            const float* __restrict__ alpha, const float* __restrict__ beta,
                            const float* __restrict__ U_tail, const float* __restrict__ S_tail,
                            float* __restrict__ A1, float* __restrict__ A2) {
  int idx = blockIdx.x * 256 + threadIdx.x;       // over OUT_DIM*RANK
  int r = idx & (RANK - 1);
  float sig = S_top[r] * alpha[r] + beta[r];
  sig = sig > 0.f ? sig : 0.f;
  A1[idx] = U_top[idx] * sig;
  A2[idx] = U_tail[idx] * S_tail[r];
}

// ============ kernel 2: RV = R @ Vh_tail  (64 x IN) ============
__global__ void rv_kernel(const float* __restrict__ Rm, const float* __restrict__ Vh_tail,
                          float* __restrict__ RV) {
  int i = blockIdx.x * 256 + threadIdx.x;         // 0..IN_DIM-1
  float v[RANK];
#pragma unroll
  for (int q = 0; q < RANK; ++q) v[q] = Vh_tail[q * IN_DIM + i];
  for (int r = 0; r < RANK; ++r) {
    float acc = 0.f;
#pragma unroll
    for (int q = 0; q < RANK; ++q) acc = fmaf(Rm[r * RANK + q], v[q], acc);
    RV[r * IN_DIM + i] = acc;
  }
}

// ============ kernel 3: x -> bf16 ============
__global__ void cvt_kernel(const float* __restrict__ x, unsigned short* __restrict__ xb) {
  const long long n8 = (long long)M_DIM * IN_DIM / 8;
  long long idx = (long long)blockIdx.x * blockDim.x + threadIdx.x;
  const long long stride = (long long)gridDim.x * blockDim.x;
  for (; idx < n8; idx += stride) {
    const f32x4* p = (const f32x4*)(x + idx * 8);
    f32x4 v0 = p[0], v1 = p[1];
    s16x8 o;
    o[0] = (short)f2bf(v0[0]); o[1] = (short)f2bf(v0[1]);
    o[2] = (short)f2bf(v0[2]); o[3] = (short)f2bf(v0[3]);
    o[4] = (short)f2bf(v1[0]); o[5] = (short)f2bf(v1[1]);
    o[6] = (short)f2bf(v1[2]); o[7] = (short)f2bf(v1[3]);
    *(s16x8*)(xb + idx * 8) = o;
  }
}

// ============ kernel 4: W_tilde (bf16, [OUT][IN] = B^T layout) ============
#define WT_O 16
__global__ void wtilde_kernel(const float* __restrict__ W,  const float* __restrict__ A1,
                              const float* __restrict__ A2, const float* __restrict__ Vh_top,
                              const float* __restrict__ RV, unsigned short* __restrict__ Wb) {
  const int i  = blockIdx.x * 256 + threadIdx.x;
  const int o0 = blockIdx.y * WT_O;
  float acc[WT_O];
#pragma unroll
  for (int o = 0; o < WT_O; ++o) acc[o] = W[(size_t)(o0 + o) * IN_DIM + i];
#pragma unroll 4
  for (int r = 0; r < RANK; ++r) {
    float vt = Vh_top[(size_t)r * IN_DIM + i];
    float rv = RV[(size_t)r * IN_DIM + i];
#pragma unroll
    for (int o = 0; o < WT_O; ++o) {
      acc[o] = fmaf(A1[(o0 + o) * RANK + r], vt, acc[o]);   // uniform -> s_load
      acc[o] = fmaf(A2[(o0 + o) * RANK + r], rv, acc[o]);
    }
  }
#pragma unroll
  for (int o = 0; o < WT_O; ++o)
    Wb[(size_t)(o0 + o) * IN_DIM + i] = f2bf(acc[o]);
}

// ============ kernel 5: GEMM  C[m][n] = sum_k xb[m][k]*Wb[n][k] + bias[n] ============
#define BM 128
#define BN 128
#define BK 32

__global__ __launch_bounds__(256) void gemm_kernel(
    const unsigned short* __restrict__ A,   // xb [M][K] bf16 bits
    const unsigned short* __restrict__ Bw,  // Wb [N][K] bf16 bits
    const float* __restrict__ bias,
    float* __restrict__ C) {
  __shared__ unsigned short As[BM * BK];   // 8 KB
  __shared__ unsigned short Bs[BN * BK];   // 8 KB

  const int tid = threadIdx.x;
  const int l   = tid & 63;
  const int w   = tid >> 6;
  const int wr  = w >> 1;                  // 2x2 wave grid
  const int wc  = w & 1;
  const long long tileM = (long long)blockIdx.y * BM;
  const long long tileN = (long long)blockIdx.x * BN;

  // staging: 512 chunks of 16B per matrix tile; chunk c -> row c/4, col-chunk c%4
  const int c0 = tid;
  const int c1 = tid + 256;
  const unsigned short* ga0 = A  + (tileM + (c0 >> 2)) * IN_DIM + (c0 & 3) * 8;
  const unsigned short* ga1 = A  + (tileM + (c1 >> 2)) * IN_DIM + (c1 & 3) * 8;
  const unsigned short* gb0 = Bw + (tileN + (c0 >> 2)) * IN_DIM + (c0 & 3) * 8;
  const unsigned short* gb1 = Bw + (tileN + (c1 >> 2)) * IN_DIM + (c1 & 3) * 8;
  unsigned short* la0 = &As[c0 * 8];
  unsigned short* la1 = &As[c1 * 8];
  unsigned short* lb0 = &Bs[c0 * 8];
  unsigned short* lb1 = &Bs[c1 * 8];

  f32x4 acc[4][4] = {};

  const int arow  = wr * 64 + (l & 15);    // + m*16
  const int brow  = wc * 64 + (l & 15);    // + n*16
  const int koff8 = (l >> 4) * 8;          // k-chunk within BK

  for (int kt = 0; kt < IN_DIM; kt += BK) {
    gload16(ga0 + kt, la0);
    gload16(ga1 + kt, la1);
    gload16(gb0 + kt, lb0);
    gload16(gb1 + kt, lb1);
    __syncthreads();                       // drains vmcnt -> LDS valid

    s16x8 af[4], bf[4];
#pragma unroll
    for (int m = 0; m < 4; ++m) af[m] = *(const s16x8*)&As[(arow + m * 16) * BK + koff8];
#pragma unroll
    for (int n = 0; n < 4; ++n) bf[n] = *(const s16x8*)&Bs[(brow + n * 16) * BK + koff8];
#pragma unroll
    for (int m = 0; m < 4; ++m)
#pragma unroll
      for (int n = 0; n < 4; ++n)
        acc[m][n] = mfma_bf16(af[m], bf[n], acc[m][n]);

    __syncthreads();                       // all reads done before next stage
  }

  // epilogue: D row = m*16 + 4*(l>>4)+reg, col = n*16 + (l&15)  [m89-verified layout]
  float bv[4];
#pragma unroll
  for (int n = 0; n < 4; ++n) bv[n] = bias[tileN + wc * 64 + n * 16 + (l & 15)];
#pragma unroll
  for (int m = 0; m < 4; ++m) {
    const long long rbase = tileM + wr * 64 + m * 16 + (l >> 4) * 4;
#pragma unroll
    for (int r = 0; r < 4; ++r) {
      float* crow = C + (size_t)(rbase + r) * OUT_DIM + tileN + wc * 64 + (l & 15);
#pragma unroll
      for (int n = 0; n < 4; ++n) crow[n * 16] = acc[m][n][r] + bv[n];
    }
  }
}

extern "C" void kernel_launch(void* const* d_in, const int* in_sizes, int n_in,
                              void* d_out, int out_size, void* d_ws, size_t ws_size,
                              hipStream_t stream) {
  const float* x       = (const float*)d_in[0];
  const float* W       = (const float*)d_in[1];
  const float* bias    = (const float*)d_in[2];
  const float* U_top   = (const float*)d_in[3];
  const float* S_top   = (const float*)d_in[4];
  const float* Vh_top  = (const float*)d_in[5];
  const float* U_tail  = (const float*)d_in[6];
  const float* S_tail  = (const float*)d_in[7];
  const float* Vh_tail = (const float*)d_in[8];
  const float* alpha   = (const float*)d_in[9];
  const float* beta    = (const float*)d_in[10];
  const float* Rm      = (const float*)d_in[11];

  // workspace layout (needs ~163 MB)
  char* ws = (char*)d_ws;
  unsigned short* xb = (unsigned short*)ws;                                   // 128 MB
  unsigned short* Wb = (unsigned short*)(ws + (size_t)134217728);             // 32 MB
  float* A1 = (float*)(ws + (size_t)134217728 + 33554432);                    // 1 MB
  float* A2 = A1 + (size_t)OUT_DIM * RANK;                                    // 1 MB
  float* RV = A2 + (size_t)OUT_DIM * RANK;                                    // 1 MB

  prep_kernel<<<(OUT_DIM * RANK) / 256, 256, 0, stream>>>(U_top, S_top, alpha, beta,
                                                          U_tail, S_tail, A1, A2);
  rv_kernel<<<IN_DIM / 256, 256, 0, stream>>>(Rm, Vh_tail, RV);
  cvt_kernel<<<2048, 256, 0, stream>>>(x, xb);
  wtilde_kernel<<<dim3(IN_DIM / 256, OUT_DIM / WT_O), 256, 0, stream>>>(W, A1, A2,
                                                                        Vh_top, RV, Wb);
  gemm_kernel<<<dim3(OUT_DIM / BN, M_DIM / BM), 256, 0, stream>>>(xb, Wb, bias,
                                                                  (float*)d_out);
}

// Round 3
// 751.038 us; speedup vs baseline: 1.2280x; 1.2280x over previous
//
#include <hip/hip_runtime.h>
#include <hip/hip_bf16.h>

#define OUT_DIM 4096
#define IN_DIM  4096
#define RANK    64
#define M_DIM   16384   // B*S = 4*4096

typedef short  s16x8 __attribute__((ext_vector_type(8)));
typedef __bf16 b16x8 __attribute__((ext_vector_type(8)));
typedef float  f32x4 __attribute__((ext_vector_type(4)));

// ---- MFMA wrapper: tolerate either builtin signature (short8 or bf16x8) ----
template <typename T>
__device__ static inline auto mfma_sel(T a, T b, f32x4 c, int)
    -> decltype(__builtin_amdgcn_mfma_f32_16x16x32_bf16(a, b, c, 0, 0, 0)) {
  return __builtin_amdgcn_mfma_f32_16x16x32_bf16(a, b, c, 0, 0, 0);
}
template <typename T>
__device__ static inline f32x4 mfma_sel(T a, T b, f32x4 c, long) {
  return __builtin_amdgcn_mfma_f32_16x16x32_bf16(
      __builtin_bit_cast(b16x8, a), __builtin_bit_cast(b16x8, b), c, 0, 0, 0);
}
__device__ static inline f32x4 mfma_bf16(s16x8 a, s16x8 b, f32x4 c) {
  return mfma_sel(a, b, c, 0);
}

// ---- fp32 -> bf16 bits, round-to-nearest-even ----
__device__ static inline unsigned short f2bf(float f) {
  unsigned int u = __float_as_uint(f);
  u += 0x7fffu + ((u >> 16) & 1u);
  return (unsigned short)(u >> 16);
}

// ---- async global->LDS, 16B per lane ----
__device__ static inline void gload16(const unsigned short* g, unsigned short* l) {
  __builtin_amdgcn_global_load_lds(
      (const __attribute__((address_space(1))) void*)g,
      (__attribute__((address_space(3))) void*)l, 16, 0, 0);
}

// ============ kernel 1: sigma gating + scaled factors ============
__global__ void prep_kernel(const float* __restrict__ U_top, const float* __restrict__ S_top,
                            const float* __restrict__ alpha, const float* __restrict__ beta,
                            const float* __restrict__ U_tail, const float* __restrict__ S_tail,
                            float* __restrict__ A1, float* __restrict__ A2) {
  int idx = blockIdx.x * 256 + threadIdx.x;       // over OUT_DIM*RANK
  int r = idx & (RANK - 1);
  float sig = S_top[r] * alpha[r] + beta[r];
  sig = sig > 0.f ? sig : 0.f;
  A1[idx] = U_top[idx] * sig;
  A2[idx] = U_tail[idx] * S_tail[r];
}

// ============ kernel 2: RV = R @ Vh_tail  (64 x IN) ============
__global__ void rv_kernel(const float* __restrict__ Rm, const float* __restrict__ Vh_tail,
                          float* __restrict__ RV) {
  int i = blockIdx.x * 256 + threadIdx.x;         // 0..IN_DIM-1
  float v[RANK];
#pragma unroll
  for (int q = 0; q < RANK; ++q) v[q] = Vh_tail[q * IN_DIM + i];
  for (int r = 0; r < RANK; ++r) {
    float acc = 0.f;
#pragma unroll
    for (int q = 0; q < RANK; ++q) acc = fmaf(Rm[r * RANK + q], v[q], acc);
    RV[r * IN_DIM + i] = acc;
  }
}

// ============ kernel 3: x -> bf16 ============
__global__ void cvt_kernel(const float* __restrict__ x, unsigned short* __restrict__ xb) {
  const long long n8 = (long long)M_DIM * IN_DIM / 8;
  long long idx = (long long)blockIdx.x * blockDim.x + threadIdx.x;
  const long long stride = (long long)gridDim.x * blockDim.x;
  for (; idx < n8; idx += stride) {
    const f32x4* p = (const f32x4*)(x + idx * 8);
    f32x4 v0 = p[0], v1 = p[1];
    s16x8 o;
    o[0] = (short)f2bf(v0[0]); o[1] = (short)f2bf(v0[1]);
    o[2] = (short)f2bf(v0[2]); o[3] = (short)f2bf(v0[3]);
    o[4] = (short)f2bf(v1[0]); o[5] = (short)f2bf(v1[1]);
    o[6] = (short)f2bf(v1[2]); o[7] = (short)f2bf(v1[3]);
    *(s16x8*)(xb + idx * 8) = o;
  }
}

// ============ kernel 4: W_tilde (bf16, [OUT][IN] = B^T layout) ============
#define WT_O 16
__global__ void wtilde_kernel(const float* __restrict__ W,  const float* __restrict__ A1,
                              const float* __restrict__ A2, const float* __restrict__ Vh_top,
                              const float* __restrict__ RV, unsigned short* __restrict__ Wb) {
  const int i  = blockIdx.x * 256 + threadIdx.x;
  const int o0 = blockIdx.y * WT_O;
  float acc[WT_O];
#pragma unroll
  for (int o = 0; o < WT_O; ++o) acc[o] = W[(size_t)(o0 + o) * IN_DIM + i];
#pragma unroll 4
  for (int r = 0; r < RANK; ++r) {
    float vt = Vh_top[(size_t)r * IN_DIM + i];
    float rv = RV[(size_t)r * IN_DIM + i];
#pragma unroll
    for (int o = 0; o < WT_O; ++o) {
      acc[o] = fmaf(A1[(o0 + o) * RANK + r], vt, acc[o]);
      acc[o] = fmaf(A2[(o0 + o) * RANK + r], rv, acc[o]);
    }
  }
#pragma unroll
  for (int o = 0; o < WT_O; ++o)
    Wb[(size_t)(o0 + o) * IN_DIM + i] = f2bf(acc[o]);
}

// ============ kernel 5: 256x256 8-phase GEMM ============
// C[m][n] = sum_k xb[m][k]*Wb[n][k] + bias[n]
// 8 waves (2M x 4N), BK=64, double-buffered 128KiB LDS, counted vmcnt,
// chunk-XOR LDS swizzle (c ^= row&7), XCD-aware block swizzle.
#define BM 256
#define BN 256
#define BK 64
#define NT (IN_DIM / BK)   // 64

__global__ __launch_bounds__(512, 2) void gemm_kernel(
    const unsigned short* __restrict__ A,   // xb [M][K] bf16 bits
    const unsigned short* __restrict__ Bw,  // Wb [N][K] bf16 bits
    const float* __restrict__ bias,
    float* __restrict__ C) {
  // [buf][mat(0=A,1=B)][256*64 elems]  = 128 KiB
  __shared__ unsigned short lds[2][2][BM * BK];

  const int tid = threadIdx.x;
  const int l   = tid & 63;
  const int wid = tid >> 6;
  const int wr  = wid >> 2;                 // 0..1  (M split)
  const int wc  = wid & 3;                  // 0..3  (N split)

  // XCD swizzle: 1024 blocks, 8 XCDs, nwg%8==0 -> simple bijection.
  // Each XCD gets 128 consecutive swz ids = 2 N-panels x all 64 M-tiles
  // -> per-XCD L2 working set = 2 B-panels (4 MB), fits L2.
  const int bid = blockIdx.x;
  const int swz = (bid & 7) * 128 + (bid >> 3);
  const int nt_ = swz >> 6;                 // 0..15
  const int mt_ = swz & 63;                 // 0..63
  const long long tileM = (long long)mt_ * BM;
  const long long tileN = (long long)nt_ * BN;

  // ---- staging geometry (linear LDS dest, inverse-swizzled global src) ----
  // load j of a matrix region covers elements [j*4096, (j+1)*4096): rows j*64..j*64+63
  // thread: rbase = tid>>3 (row within 64-row group), phys chunk = tid&7
  // logical chunk = phys ^ (row&7); row&7 == rbase&7 (j*64 = 0 mod 8)
  const int rbase = tid >> 3;
  const int c8    = (((tid & 7) ^ (rbase & 7)) << 3);       // element offset in row
  const unsigned short* gA = A  + (tileM + rbase) * (long long)IN_DIM + c8;
  const unsigned short* gB = Bw + (tileN + rbase) * (long long)IN_DIM + c8;

  // ---- ds_read geometry ----
  const int kgrp = l >> 4;                  // 0..3
  const int x7   = l & 7;                   // row&7 for all frag rows
  const int sc0  = (((0 * 4 + kgrp) ^ x7) << 3);   // kk=0 chunk, elements
  const int sc1  = (((1 * 4 + kgrp) ^ x7) << 3);   // kk=1
  const int rba  = (wr * 128 + (l & 15)) * BK;     // element base, A region
  const int rbb  = (wc * 64  + (l & 15)) * BK;     // element base, B region

  f32x4 acc[8][4] = {};

  // ---- prologue: stage tile 0 fully, drain, barrier ----
  {
    unsigned short* la = &lds[0][0][tid * 8];
    unsigned short* lb = &lds[0][1][tid * 8];
#pragma unroll
    for (int j = 0; j < 4; ++j) {
      gload16(gB + (long long)j * 64 * IN_DIM, lb + j * 4096);
      gload16(gA + (long long)j * 64 * IN_DIM, la + j * 4096);
    }
    asm volatile("s_waitcnt vmcnt(0)" ::: "memory");
    asm volatile("s_barrier" ::: "memory");
  }

  int buf = 0;
  for (int t = 0; t < NT; ++t) {
    const long long ktn = (long long)(t + 1) * BK;
    const bool more = (t + 1 < NT);
    const unsigned short* lA = lds[buf][0];
    const unsigned short* lB = lds[buf][1];
    unsigned short* la1 = &lds[buf ^ 1][0][tid * 8];
    unsigned short* lb1 = &lds[buf ^ 1][1][tid * 8];

    s16x8 bfr[4][2];
#pragma unroll
    for (int q = 0; q < 4; ++q) {
      // --- ds reads for this phase (from buf) ---
      if (q == 0) {
#pragma unroll
        for (int n = 0; n < 4; ++n) {
          bfr[n][0] = *(const s16x8*)&lB[rbb + n * 16 * BK + sc0];
          bfr[n][1] = *(const s16x8*)&lB[rbb + n * 16 * BK + sc1];
        }
      }
      s16x8 afr[2][2];
#pragma unroll
      for (int m2 = 0; m2 < 2; ++m2) {
        afr[m2][0] = *(const s16x8*)&lA[rba + (q * 32 + m2 * 16) * BK + sc0];
        afr[m2][1] = *(const s16x8*)&lA[rba + (q * 32 + m2 * 16) * BK + sc1];
      }

      // --- stage item q of tile t+1 into buf^1 ---
      // q=0: B rows 0-127 | q=1: B rows 128-255 | q=2: A loads {0,2} | q=3: A loads {1,3}
      if (more) {
        if (q == 0) {
          gload16(gB + ktn, lb1);
          gload16(gB + ktn + 1LL * 64 * IN_DIM, lb1 + 4096);
        } else if (q == 1) {
          gload16(gB + ktn + 2LL * 64 * IN_DIM, lb1 + 2 * 4096);
          gload16(gB + ktn + 3LL * 64 * IN_DIM, lb1 + 3 * 4096);
        } else if (q == 2) {
          gload16(gA + ktn, la1);
          gload16(gA + ktn + 2LL * 64 * IN_DIM, la1 + 2 * 4096);
        } else {
          gload16(gA + ktn + 1LL * 64 * IN_DIM, la1 + 1 * 4096);
          gload16(gA + ktn + 3LL * 64 * IN_DIM, la1 + 3 * 4096);
        }
      }

      asm volatile("s_barrier" ::: "memory");

      __builtin_amdgcn_s_setprio(1);
#pragma unroll
      for (int m2 = 0; m2 < 2; ++m2)
#pragma unroll
        for (int n = 0; n < 4; ++n)
#pragma unroll
          for (int kk = 0; kk < 2; ++kk)
            acc[q * 2 + m2][n] = mfma_bf16(afr[m2][kk], bfr[n][kk], acc[q * 2 + m2][n]);
      __builtin_amdgcn_s_setprio(0);

      // --- phase-closing waits (counted, never 0 in steady state) ---
      if (q == 1) {
        // need AL2(t) landed before phase 2 reads; 4 newest = B0,B1(t+1)
        if (more) asm volatile("s_waitcnt vmcnt(4)" ::: "memory");
        else      asm volatile("s_waitcnt vmcnt(0)" ::: "memory");
      }
      if (q == 3 && more) {
        // need B0,B1,AL1(t+1) landed before next tile; 2 newest = AL2(t+1)
        asm volatile("s_waitcnt vmcnt(2)" ::: "memory");
      }
      asm volatile("s_barrier" ::: "memory");
    }
    buf ^= 1;
  }

  // ---- epilogue: D row = m*16 + (l>>4)*4 + r ; col = n*16 + (l&15) ----
  float bv[4];
#pragma unroll
  for (int n = 0; n < 4; ++n) bv[n] = bias[tileN + wc * 64 + n * 16 + (l & 15)];
#pragma unroll
  for (int m = 0; m < 8; ++m) {
    const long long rbase_c = tileM + wr * 128 + m * 16 + (l >> 4) * 4;
#pragma unroll
    for (int r = 0; r < 4; ++r) {
      float* crow = C + (size_t)(rbase_c + r) * OUT_DIM + tileN + wc * 64 + (l & 15);
#pragma unroll
      for (int n = 0; n < 4; ++n) crow[n * 16] = acc[m][n][r] + bv[n];
    }
  }
}

extern "C" void kernel_launch(void* const* d_in, const int* in_sizes, int n_in,
                              void* d_out, int out_size, void* d_ws, size_t ws_size,
                              hipStream_t stream) {
  const float* x       = (const float*)d_in[0];
  const float* W       = (const float*)d_in[1];
  const float* bias    = (const float*)d_in[2];
  const float* U_top   = (const float*)d_in[3];
  const float* S_top   = (const float*)d_in[4];
  const float* Vh_top  = (const float*)d_in[5];
  const float* U_tail  = (const float*)d_in[6];
  const float* S_tail  = (const float*)d_in[7];
  const float* Vh_tail = (const float*)d_in[8];
  const float* alpha   = (const float*)d_in[9];
  const float* beta    = (const float*)d_in[10];
  const float* Rm      = (const float*)d_in[11];

  char* ws = (char*)d_ws;
  unsigned short* xb = (unsigned short*)ws;                                   // 128 MB
  unsigned short* Wb = (unsigned short*)(ws + (size_t)134217728);             // 32 MB
  float* A1 = (float*)(ws + (size_t)134217728 + 33554432);
  float* A2 = A1 + (size_t)OUT_DIM * RANK;
  float* RV = A2 + (size_t)OUT_DIM * RANK;

  prep_kernel<<<(OUT_DIM * RANK) / 256, 256, 0, stream>>>(U_top, S_top, alpha, beta,
                                                          U_tail, S_tail, A1, A2);
  rv_kernel<<<IN_DIM / 256, 256, 0, stream>>>(Rm, Vh_tail, RV);
  cvt_kernel<<<2048, 256, 0, stream>>>(x, xb);
  wtilde_kernel<<<dim3(IN_DIM / 256, OUT_DIM / WT_O), 256, 0, stream>>>(W, A1, A2,
                                                                        Vh_top, RV, Wb);
  gemm_kernel<<<(M_DIM / BM) * (OUT_DIM / BN), 512, 0, stream>>>(xb, Wb, bias,
                                                                 (float*)d_out);
}